// Round 12
// baseline (1310.621 us; speedup 1.0000x reference)
//
#include <hip/hip_runtime.h>
#include <cstdint>
#include <cstddef>

static constexpr int kNS = 100000;
static constexpr int kNC = 512;
static constexpr int kES = 3200000;
static constexpr int kEC = 16384;

static constexpr int kNB = (kNS + 63) / 64;        // 1563 coarse buckets
static constexpr int kNB8 = kNB * 8;
static constexpr int kCHUNK = 8192;
static constexpr int kNBLK = (kES + kCHUNK - 1) / kCHUNK;  // 391

static constexpr int kGemmQBlocks = (kNS + 63) / 64;   // 1563
static constexpr int kAgg64Blocks = (kNS + 7) / 8;     // 12500
static constexpr int kG1 = 625;
static constexpr int kG2 = 469;
static constexpr int kG3 = kGemmQBlocks - kG1 - kG2;

static constexpr int kClusterSmemInts = 4608;          // cluster_body LDS layout (ints)
static constexpr int kFat0SmemInts = (kClusterSmemInts > kNB) ? kClusterSmemInts : kNB;

typedef __attribute__((ext_vector_type(8))) short short8;
typedef __attribute__((ext_vector_type(4))) float f32x4;

__device__ __forceinline__ unsigned short f2bf(float f) {
  union { float f; unsigned u; } v; v.f = f;
  unsigned u = v.u;
  unsigned r = (u + 0x7fffu + ((u >> 16) & 1u)) >> 16;
  return (unsigned short)r;
}
__device__ __forceinline__ float bflo(unsigned v) { return __uint_as_float(v << 16); }
__device__ __forceinline__ float bfhi(unsigned v) { return __uint_as_float(v & 0xffff0000u); }
__device__ __forceinline__ float bf2f(unsigned short s) { return __uint_as_float(((unsigned)s) << 16); }
__device__ __forceinline__ unsigned pk2(float a, float b) {
  return (unsigned)f2bf(a) | ((unsigned)f2bf(b) << 16);
}

// ---------------- passA body: bucket histogram ----------------
__device__ __forceinline__ void passA_body(int bid, int t, const int* __restrict__ col, int E,
                                           int* __restrict__ counts, int* __restrict__ hist) {
  for (int j = t; j < kNB; j += 256) hist[j] = 0;
  __syncthreads();
  int base = bid * kCHUNK;
#pragma unroll 4
  for (int i = 0; i < kCHUNK / 256; i++) {
    int e = base + i * 256 + t;
    if (e < E) atomicAdd(&hist[col[e] >> 6], 1);
  }
  __syncthreads();
  int sub = bid & 7;
  for (int j = t; j < kNB; j += 256) {
    int v = hist[j];
    if (v) atomicAdd(&counts[j * 8 + sub], v);
  }
}

// ---------------- cluster mega body (single block, 256 threads; needs 4608 ints LDS) ------------
__device__ __forceinline__ void cluster_body(
    int t, const int* __restrict__ erow, const int* __restrict__ ecol,
    const float* __restrict__ x_c, const float* __restrict__ W1c, const float* __restrict__ b1c,
    const float* __restrict__ W2c, const float* __restrict__ b2c,
    const float* __restrict__ A1, const float* __restrict__ D1, const float* __restrict__ Wcls,
    const float* __restrict__ W2s,
    int* __restrict__ srow_c, unsigned short* __restrict__ yc, unsigned short* __restrict__ gtc,
    unsigned short* __restrict__ xc2b,
    short* __restrict__ Bq, short* __restrict__ A1p, short* __restrict__ Bh, short* __restrict__ W2sp,
    int* smem) {
  int* degL = smem;                        // 512
  int* startsL = smem + 512;               // 512
  int* curL = smem + 1024;                 // 512
  float* disL = (float*)(smem + 1536);     // 512
  unsigned* zL = (unsigned*)(smem + 2048); // 2048
  float* W1L = (float*)(smem + 4096);      // 448
  float* b1L = W1L + 448;                  // 64  -> total 4608 ints

  for (int i = t; i < 512; i += 256) degL[i] = 0;
  __syncthreads();
  for (int e = t; e < kEC; e += 256) atomicAdd(&degL[ecol[e]], 1);
  __syncthreads();
  for (int i = t; i < 512; i += 256) startsL[i] = degL[i];
  __syncthreads();
  for (int o = 1; o < 512; o <<= 1) {
    int i0 = t, i1 = t + 256;
    int v0 = (i0 >= o) ? startsL[i0 - o] : 0;
    int v1 = (i1 >= o) ? startsL[i1 - o] : 0;
    __syncthreads();
    startsL[i0] += v0;
    startsL[i1] += v1;
    __syncthreads();
  }
  for (int i = t; i < 512; i += 256) {
    int ex = startsL[i] - degL[i];
    curL[i] = ex;
    disL[i] = rsqrtf((float)(degL[i] + 1));
  }
  __syncthreads();
  for (int i = t; i < 512; i += 256) startsL[i] -= degL[i];  // exclusive
  for (int i = t; i < 448; i += 256) W1L[i] = W1c[i];
  if (t < 64) b1L[t] = b1c[t];
  __syncthreads();
  // scatter + z
  for (int e = t; e < kEC; e += 256) {
    int c = ecol[e];
    int pos = atomicAdd(&curL[c], 1);
    srow_c[pos] = erow[e];
  }
  for (int i = t; i < 512; i += 256) {
    float d = disL[i];
    const float* xr = x_c + (size_t)i * 7;
    zL[i * 4 + 0] = pk2(xr[0] * d, xr[1] * d);
    zL[i * 4 + 1] = pk2(xr[2] * d, xr[3] * d);
    zL[i * 4 + 2] = pk2(xr[4] * d, xr[5] * d);
    zL[i * 4 + 3] = (unsigned)f2bf(xr[6] * d);
  }
  __syncthreads();
  // agg7 + lin7b (thread per node)
  for (int c = t; c < 512; c += 256) {
    float a[7];
    {
      unsigned w0 = zL[c * 4], w1 = zL[c * 4 + 1], w2 = zL[c * 4 + 2], w3 = zL[c * 4 + 3];
      a[0] = bflo(w0); a[1] = bfhi(w0); a[2] = bflo(w1); a[3] = bfhi(w1);
      a[4] = bflo(w2); a[5] = bfhi(w2); a[6] = bflo(w3);
    }
    int s0 = startsL[c], n = degL[c];
    for (int e = 0; e < n; e++) {
      int r = srow_c[s0 + e];
      unsigned w0 = zL[r * 4], w1 = zL[r * 4 + 1], w2 = zL[r * 4 + 2], w3 = zL[r * 4 + 3];
      a[0] += bflo(w0); a[1] += bfhi(w0); a[2] += bflo(w1); a[3] += bfhi(w1);
      a[4] += bflo(w2); a[5] += bfhi(w2); a[6] += bflo(w3);
    }
    float d = disL[c];
#pragma unroll
    for (int k = 0; k < 7; k++) a[k] *= d;
    for (int j = 0; j < 64; j += 2) {
      float s0v = b1L[j], s1v = b1L[j + 1];
#pragma unroll
      for (int k = 0; k < 7; k++) {
        s0v = fmaf(a[k], W1L[k * 64 + j], s0v);
        s1v = fmaf(a[k], W1L[k * 64 + j + 1], s1v);
      }
      *(unsigned*)(yc + (size_t)c * 64 + j) = pk2(fmaxf(s0v, 0.f) * d, fmaxf(s1v, 0.f) * d);
    }
  }
  __syncthreads();
  // agg64 -> gtc (32 lanes per node)
  for (int it = 0; it < 64; it++) {
    int c = it * 8 + (t >> 5);
    int fi = (t & 31) * 2;
    unsigned v = *(const unsigned*)(yc + (size_t)c * 64 + fi);
    float ax = bflo(v), ay = bfhi(v);
    int s0 = startsL[c], n = degL[c];
    for (int e = 0; e < n; e++) {
      unsigned vv = *(const unsigned*)(yc + (size_t)srow_c[s0 + e] * 64 + fi);
      ax += bflo(vv);
      ay += bfhi(vv);
    }
    float d = disL[c];
    *(unsigned*)(gtc + (size_t)c * 64 + fi) = pk2(ax * d, ay * d);
  }
  __syncthreads();
  // lin64x128 -> xc2b
  for (int idx = t; idx < 512 * 64; idx += 256) {
    int r = idx >> 6, c2 = (idx & 63) * 2;
    float s0v = b2c[c2], s1v = b2c[c2 + 1];
    for (int k = 0; k < 64; k++) {
      float gv = bf2f(gtc[(size_t)r * 64 + k]);
      s0v = fmaf(gv, W2c[k * 128 + c2], s0v);
      s1v = fmaf(gv, W2c[k * 128 + c2 + 1], s1v);
    }
    *(unsigned*)(xc2b + (size_t)r * 128 + c2) = pk2(fmaxf(s0v, 0.f), fmaxf(s1v, 0.f));
  }
  __syncthreads();
  // packs: Bq (from xc2b), A1p, Bh, W2sp
  for (int e = t; e < 512 * 128; e += 256) {
    int k = e >> 7, n = e & 127;
    int frag = (k >> 5) * 8 + (n >> 4);
    int l = (n & 15) | (((k >> 3) & 3) << 4);
    Bq[(size_t)frag * 512 + l * 8 + (k & 7)] = (short)xc2b[e];
  }
  for (int e = t; e < 256 * 128; e += 256) {
    int k = e >> 7, n = e & 127;
    int frag = (k >> 5) * 8 + (n >> 4);
    int l = (n & 15) | (((k >> 3) & 3) << 4);
    A1p[(size_t)frag * 512 + l * 8 + (k & 7)] = (short)f2bf(A1[e]);
  }
  for (int e = t; e < 128 * 80; e += 256) {
    int k = e / 80, n = e % 80;
    float v = 0.f;
    if (n < 64) v = D1[k * 64 + n];
    else if (n < 73) v = Wcls[k * 9 + (n - 64)];
    int frag = (k >> 5) * 5 + (n >> 4);
    int l = (n & 15) | (((k >> 3) & 3) << 4);
    Bh[(size_t)frag * 512 + l * 8 + (k & 7)] = (short)f2bf(v);
  }
  for (int e = t; e < 64 * 128; e += 256) {
    int k = e >> 7, n = e & 127;
    int frag = (k >> 5) * 8 + (n >> 4);
    int l = (n & 15) | (((k >> 3) & 3) << 4);
    W2sp[(size_t)frag * 512 + l * 8 + (k & 7)] = (short)f2bf(W2s[e]);
  }
}

// ---------------- fat0: block0 = cluster mega; blocks 1.. = passA ----------------
__global__ __launch_bounds__(256) void k_fat0(
    const int* __restrict__ erow_c, const int* __restrict__ ecol_c,
    const float* __restrict__ x_c, const float* __restrict__ W1c, const float* __restrict__ b1c,
    const float* __restrict__ W2c, const float* __restrict__ b2c,
    const float* __restrict__ A1, const float* __restrict__ D1, const float* __restrict__ Wcls,
    const float* __restrict__ W2s,
    int* __restrict__ srow_c, unsigned short* __restrict__ yc, unsigned short* __restrict__ gtc,
    unsigned short* __restrict__ xc2b,
    short* __restrict__ Bq, short* __restrict__ A1p, short* __restrict__ Bh, short* __restrict__ W2sp,
    const int* __restrict__ scol, int E, int* __restrict__ counts) {
  __shared__ int smem[kFat0SmemInts];
  int bid = blockIdx.x, t = threadIdx.x;
  if (bid == 0) {
    cluster_body(t, erow_c, ecol_c, x_c, W1c, b1c, W2c, b2c, A1, D1, Wcls, W2s,
                 srow_c, yc, gtc, xc2b, Bq, A1p, Bh, W2sp, smem);
  } else {
    passA_body(bid - 1, t, scol, E, counts, smem);
  }
}

// exclusive scan of n flat counters -> starts[n+1], cursor copy
__global__ void k_scan_flat(const int* __restrict__ cnt, int n, int* __restrict__ starts,
                            int* __restrict__ cursor) {
  __shared__ int s[256];
  int t = threadIdx.x;
  int run = 0;
  for (int base = 0; base < n; base += 256) {
    int i = base + t;
    int v = (i < n) ? cnt[i] : 0;
    s[t] = v;
    __syncthreads();
    for (int o = 1; o < 256; o <<= 1) {
      int x = (t >= o) ? s[t - o] : 0;
      __syncthreads();
      s[t] += x;
      __syncthreads();
    }
    if (i < n) {
      int ex = run + s[t] - v;
      starts[i] = ex;
      cursor[i] = ex;
    }
    int tot = s[255];
    __syncthreads();
    run += tot;
  }
  if (t == 0) starts[n] = run;
}

// ---------------- passB body ----------------
__device__ __forceinline__ void passB_body(int bid, int t, const int* __restrict__ row,
                                           const int* __restrict__ col, int E,
                                           int* __restrict__ cursor, unsigned* __restrict__ edg) {
  __shared__ int hist[kNB];
  int sub = bid & 7;
  for (int j = t; j < kNB; j += 256) hist[j] = 0;
  __syncthreads();
  int base = bid * kCHUNK;
#pragma unroll 4
  for (int i = 0; i < kCHUNK / 256; i++) {
    int e = base + i * 256 + t;
    if (e < E) atomicAdd(&hist[col[e] >> 6], 1);
  }
  __syncthreads();
  for (int j = t; j < kNB; j += 256) {
    int v = hist[j];
    hist[j] = v ? atomicAdd(&cursor[j * 8 + sub], v) : 0;
  }
  __syncthreads();
#pragma unroll 4
  for (int i = 0; i < kCHUNK / 256; i++) {
    int e = base + i * 256 + t;
    if (e < E) {
      int c = col[e];
      int pos = atomicAdd(&hist[c >> 6], 1);
      edg[pos] = ((unsigned)row[e] << 6) | (unsigned)(c & 63);
    }
  }
}

// ---------------- passC body: CSR + dis + z ----------------
__device__ __forceinline__ void passC_body(int b, int t, const unsigned* __restrict__ edg,
                                           const int* __restrict__ bstarts,
                                           int* __restrict__ deg, int* __restrict__ nstarts,
                                           float* __restrict__ dis, int* __restrict__ srow,
                                           const float* __restrict__ x, unsigned* __restrict__ z, int N) {
  __shared__ int ldeg[64];
  __shared__ int lcur[64];
  int s0 = bstarts[b * 8], s1 = bstarts[b * 8 + 8];
  if (t < 64) ldeg[t] = 0;
  __syncthreads();
  for (int i = s0 + t; i < s1; i += 256) atomicAdd(&ldeg[edg[i] & 63u], 1);
  __syncthreads();
  if (t < 64) {
    int own = ldeg[t];
    int incl = own;
#pragma unroll
    for (int off = 1; off < 64; off <<= 1) {
      int o = __shfl_up(incl, off);
      if (t >= off) incl += o;
    }
    int st = s0 + incl - own;
    lcur[t] = st;
    int g = b * 64 + t;
    if (g < N) {
      deg[g] = own;
      nstarts[g] = st;
      float d = rsqrtf((float)(own + 1));
      dis[g] = d;
      const float* xr = x + (size_t)g * 7;
      uint4 o4 = {pk2(xr[0] * d, xr[1] * d), pk2(xr[2] * d, xr[3] * d),
                  pk2(xr[4] * d, xr[5] * d), (unsigned)f2bf(xr[6] * d)};
      *(uint4*)(z + (size_t)g * 4) = o4;
    }
  }
  __syncthreads();
  for (int i = s0 + t; i < s1; i += 256) {
    unsigned ew = edg[i];
    int pos = atomicAdd(&lcur[ew & 63u], 1);
    srow[pos] = (int)(ew >> 6);
  }
}

// ---------------- agg64 body ----------------
__device__ __forceinline__ void agg64_body(int bid, int t,
                                           const unsigned short* __restrict__ ys,
                                           const int* __restrict__ starts, const int* __restrict__ cnt,
                                           const int* __restrict__ srow, const float* __restrict__ dis,
                                           unsigned short* __restrict__ out, int N) {
  constexpr int F = 64, LPN = 32;
  int c = bid * (256 / LPN) + t / LPN;
  if (c >= N) return;
  int fi = (t % LPN) * 2;
  unsigned v = *(const unsigned*)(ys + (size_t)c * F + fi);
  float ax = bflo(v), ay = bfhi(v);
  int s0 = starts[c], n = cnt[c];
  const int* sp = srow + s0;
  int e = 0;
  for (; e + 8 <= n; e += 8) {
    int r0 = sp[e], r1 = sp[e + 1], r2 = sp[e + 2], r3 = sp[e + 3];
    int r4 = sp[e + 4], r5 = sp[e + 5], r6 = sp[e + 6], r7 = sp[e + 7];
    unsigned v0 = *(const unsigned*)(ys + (size_t)r0 * F + fi);
    unsigned v1 = *(const unsigned*)(ys + (size_t)r1 * F + fi);
    unsigned v2 = *(const unsigned*)(ys + (size_t)r2 * F + fi);
    unsigned v3 = *(const unsigned*)(ys + (size_t)r3 * F + fi);
    unsigned v4 = *(const unsigned*)(ys + (size_t)r4 * F + fi);
    unsigned v5 = *(const unsigned*)(ys + (size_t)r5 * F + fi);
    unsigned v6 = *(const unsigned*)(ys + (size_t)r6 * F + fi);
    unsigned v7 = *(const unsigned*)(ys + (size_t)r7 * F + fi);
    ax += bflo(v0) + bflo(v1) + bflo(v2) + bflo(v3) + bflo(v4) + bflo(v5) + bflo(v6) + bflo(v7);
    ay += bfhi(v0) + bfhi(v1) + bfhi(v2) + bfhi(v3) + bfhi(v4) + bfhi(v5) + bfhi(v6) + bfhi(v7);
  }
  for (; e + 4 <= n; e += 4) {
    int r0 = sp[e], r1 = sp[e + 1], r2 = sp[e + 2], r3 = sp[e + 3];
    unsigned v0 = *(const unsigned*)(ys + (size_t)r0 * F + fi);
    unsigned v1 = *(const unsigned*)(ys + (size_t)r1 * F + fi);
    unsigned v2 = *(const unsigned*)(ys + (size_t)r2 * F + fi);
    unsigned v3 = *(const unsigned*)(ys + (size_t)r3 * F + fi);
    ax += bflo(v0) + bflo(v1) + bflo(v2) + bflo(v3);
    ay += bfhi(v0) + bfhi(v1) + bfhi(v2) + bfhi(v3);
  }
  for (; e < n; e++) {
    unsigned vv = *(const unsigned*)(ys + (size_t)sp[e] * F + fi);
    ax += bflo(vv);
    ay += bfhi(vv);
  }
  float d = dis[c];
  *(unsigned*)(out + (size_t)c * F + fi) = pk2(ax * d, ay * d);
}

// ---------------- fused agg7+lin7b (sample): thread per node ----------------
__global__ __launch_bounds__(256) void k_agg7lin(const unsigned* __restrict__ z,
                                                 const int* __restrict__ starts, const int* __restrict__ cnt,
                                                 const int* __restrict__ srow, const float* __restrict__ dis,
                                                 const float* __restrict__ W1, const float* __restrict__ b1,
                                                 unsigned short* __restrict__ y, int N) {
  __shared__ float WL[7 * 64];
  __shared__ float bL[64];
  int t = threadIdx.x;
  for (int j = t; j < 448; j += 256) WL[j] = W1[j];
  if (t < 64) bL[t] = b1[t];
  __syncthreads();
  int c = blockIdx.x * 256 + t;
  if (c >= N) return;
  float a[7];
  {
    uint4 v = *(const uint4*)(z + (size_t)c * 4);
    a[0] = bflo(v.x); a[1] = bfhi(v.x); a[2] = bflo(v.y); a[3] = bfhi(v.y);
    a[4] = bflo(v.z); a[5] = bfhi(v.z); a[6] = bflo(v.w);
  }
  int s0 = starts[c], n = cnt[c];
  const int* sp = srow + s0;
  int e = 0;
  for (; e + 4 <= n; e += 4) {
    uint4 w0 = *(const uint4*)(z + (size_t)sp[e] * 4);
    uint4 w1 = *(const uint4*)(z + (size_t)sp[e + 1] * 4);
    uint4 w2 = *(const uint4*)(z + (size_t)sp[e + 2] * 4);
    uint4 w3 = *(const uint4*)(z + (size_t)sp[e + 3] * 4);
    a[0] += bflo(w0.x) + bflo(w1.x) + bflo(w2.x) + bflo(w3.x);
    a[1] += bfhi(w0.x) + bfhi(w1.x) + bfhi(w2.x) + bfhi(w3.x);
    a[2] += bflo(w0.y) + bflo(w1.y) + bflo(w2.y) + bflo(w3.y);
    a[3] += bfhi(w0.y) + bfhi(w1.y) + bfhi(w2.y) + bfhi(w3.y);
    a[4] += bflo(w0.z) + bflo(w1.z) + bflo(w2.z) + bflo(w3.z);
    a[5] += bfhi(w0.z) + bfhi(w1.z) + bfhi(w2.z) + bfhi(w3.z);
    a[6] += bflo(w0.w) + bflo(w1.w) + bflo(w2.w) + bflo(w3.w);
  }
  for (; e < n; e++) {
    uint4 w = *(const uint4*)(z + (size_t)sp[e] * 4);
    a[0] += bflo(w.x); a[1] += bfhi(w.x); a[2] += bflo(w.y); a[3] += bfhi(w.y);
    a[4] += bflo(w.z); a[5] += bfhi(w.z); a[6] += bflo(w.w);
  }
  float d = dis[c];
#pragma unroll
  for (int k = 0; k < 7; k++) a[k] *= d;
  unsigned ow[32];
#pragma unroll
  for (int j2 = 0; j2 < 32; j2++) {
    int j = j2 * 2;
    float s0v = bL[j], s1v = bL[j + 1];
#pragma unroll
    for (int k = 0; k < 7; k++) {
      s0v = fmaf(a[k], WL[k * 64 + j], s0v);
      s1v = fmaf(a[k], WL[k * 64 + j + 1], s1v);
    }
    ow[j2] = pk2(fmaxf(s0v, 0.f) * d, fmaxf(s1v, 0.f) * d);
  }
  uint4* op = (uint4*)(y + (size_t)c * 64);
#pragma unroll
  for (int q = 0; q < 8; q++) {
    uint4 v = {ow[q * 4], ow[q * 4 + 1], ow[q * 4 + 2], ow[q * 4 + 3]};
    op[q] = v;
  }
}

__device__ __forceinline__ short8 zero8() {
  short8 z;
#pragma unroll
  for (int j = 0; j < 8; j++) z[j] = 0;
  return z;
}

__device__ __forceinline__ short8 cvt8(float4 v0, float4 v1) {
  short8 r;
  r[0] = (short)f2bf(v0.x); r[1] = (short)f2bf(v0.y); r[2] = (short)f2bf(v0.z); r[3] = (short)f2bf(v0.w);
  r[4] = (short)f2bf(v1.x); r[5] = (short)f2bf(v1.y); r[6] = (short)f2bf(v1.z); r[7] = (short)f2bf(v1.w);
  return r;
}

// ---------------- gemm_q body (64 rows/block, 16 rows/wave, reg double-buffered) ----------------
__device__ __forceinline__ void gemm_q_body(int bid, int t, const float* __restrict__ Q,
                                            const short* __restrict__ Bp,
                                            unsigned short* __restrict__ outb, int M) {
  int lane = t & 63;
  int wid = t >> 6;
  int m0 = bid * 64 + wid * 16;
  int mrow = lane & 15;
  int kg = lane >> 4;
  f32x4 acc[8];
#pragma unroll
  for (int nf = 0; nf < 8; nf++) acc[nf] = (f32x4){0.f, 0.f, 0.f, 0.f};
  int r0 = m0 + mrow;
  bool ok = r0 < M;
  const float* ap = Q + (size_t)r0 * 512 + kg * 8;
  const short* bl = Bp + lane * 8;
  float4 z4 = {0.f, 0.f, 0.f, 0.f};
  float4 v0 = ok ? *(const float4*)ap : z4;
  float4 v1 = ok ? *(const float4*)(ap + 4) : z4;
  for (int ks = 0; ks < 16; ks++) {
    float4 n0 = z4, n1 = z4;
    if (ks < 15 && ok) {
      n0 = *(const float4*)(ap + (ks + 1) * 32);
      n1 = *(const float4*)(ap + (ks + 1) * 32 + 4);
    }
    short8 a = cvt8(v0, v1);
    const short* bb = bl + (ks << 12);
#pragma unroll
    for (int nf = 0; nf < 8; nf++) {
      short8 b = *(const short8*)(bb + (nf << 9));
      acc[nf] = __builtin_amdgcn_mfma_f32_16x16x32_bf16(a, b, acc[nf], 0, 0, 0);
    }
    v0 = n0;
    v1 = n1;
  }
  int col = lane & 15;
  int g = lane >> 4;
#pragma unroll
  for (int nf = 0; nf < 8; nf++)
#pragma unroll
    for (int r = 0; r < 4; r++) {
      int row = m0 + g * 4 + r;
      if (row < M) outb[(size_t)row * 128 + nf * 16 + col] = f2bf(acc[nf][r]);
    }
}

// ---------------- FAT kernels ----------------
__global__ __launch_bounds__(256) void k_fatB(const float* __restrict__ Q, const short* __restrict__ Bq,
                                              unsigned short* __restrict__ xcdb, int M,
                                              const int* __restrict__ row, const int* __restrict__ col, int E,
                                              int* __restrict__ cursor, unsigned* __restrict__ edg) {
  int bid = blockIdx.x, t = threadIdx.x;
  if (bid < kG1) gemm_q_body(bid, t, Q, Bq, xcdb, M);
  else passB_body(bid - kG1, t, row, col, E, cursor, edg);
}

__global__ __launch_bounds__(256) void k_fatC(const float* __restrict__ Q, const short* __restrict__ Bq,
                                              unsigned short* __restrict__ xcdb, int M,
                                              const unsigned* __restrict__ edg, const int* __restrict__ bstarts,
                                              int* __restrict__ deg, int* __restrict__ nstarts,
                                              float* __restrict__ dis, int* __restrict__ srow,
                                              const float* __restrict__ xs, unsigned* __restrict__ zs) {
  int bid = blockIdx.x, t = threadIdx.x;
  if (bid < kG2) gemm_q_body(kG1 + bid, t, Q, Bq, xcdb, M);
  else passC_body(bid - kG2, t, edg, bstarts, deg, nstarts, dis, srow, xs, zs, M);
}

__global__ __launch_bounds__(256) void k_fatA(const float* __restrict__ Q, const short* __restrict__ Bq,
                                              unsigned short* __restrict__ xcdb,
                                              const unsigned short* __restrict__ ys,
                                              const int* __restrict__ starts, const int* __restrict__ cnt,
                                              const int* __restrict__ srow, const float* __restrict__ dis,
                                              unsigned short* __restrict__ gt, int M) {
  int bid = blockIdx.x, t = threadIdx.x;
  if (bid < kG3) gemm_q_body(kG1 + kG2 + bid, t, Q, Bq, xcdb, M);
  else agg64_body(bid - kG3, t, ys, starts, cnt, srow, dis, gt, M);
}

// ---------------- TAIL: lin64x128 (MFMA) + fuse-gate + heads, LDS-staged ----------------
__global__ __launch_bounds__(256) void k_tail(const unsigned short* __restrict__ gts,
                                              const short* __restrict__ W2p, const float* __restrict__ b2,
                                              const unsigned short* __restrict__ Xc,
                                              const short* __restrict__ A1p, const float* __restrict__ ab1,
                                              const float* __restrict__ A2, const float* __restrict__ ab2,
                                              const short* __restrict__ Bh, const float* __restrict__ bcls,
                                              const float* __restrict__ db1, const float* __restrict__ D2,
                                              const float* __restrict__ db2,
                                              float* __restrict__ fused, float* __restrict__ cls_out,
                                              float* __restrict__ dom_out, int M) {
  __shared__ unsigned short xs2L[64 * 128];
  __shared__ unsigned short fusL[64 * 128];
  int t = threadIdx.x;
  int lane = t & 63;
  int wid = t >> 6;
  int m0 = blockIdx.x * 64;
  int mrow = lane & 15;
  int kg = lane >> 4;
  int rowbase = wid * 16;
  int r0 = m0 + rowbase + mrow;
  bool ok = r0 < M;
  int col16 = mrow, g = kg;

  // Stage 1: xs2 = relu(gts @ W2 + b2)
  f32x4 acc1[8];
#pragma unroll
  for (int nf = 0; nf < 8; nf++) acc1[nf] = (f32x4){0.f, 0.f, 0.f, 0.f};
#pragma unroll
  for (int ks = 0; ks < 2; ks++) {
    short8 a = ok ? *(const short8*)(gts + (size_t)r0 * 64 + ks * 32 + kg * 8) : zero8();
    const short* bb = W2p + (size_t)(ks * 8) * 512 + lane * 8;
#pragma unroll
    for (int nf = 0; nf < 8; nf++) {
      short8 b = *(const short8*)(bb + (nf << 9));
      acc1[nf] = __builtin_amdgcn_mfma_f32_16x16x32_bf16(a, b, acc1[nf], 0, 0, 0);
    }
  }
#pragma unroll
  for (int nf = 0; nf < 8; nf++)
#pragma unroll
    for (int r = 0; r < 4; r++) {
      int col = nf * 16 + col16;
      int rl = rowbase + g * 4 + r;
      float v = fmaxf(acc1[nf][r] + b2[col], 0.f);
      xs2L[rl * 128 + (((col >> 3) ^ (rl & 15)) << 3) + (col & 7)] = f2bf(v);
    }
  __syncthreads();

  // Stage 2: fuse GEMM [xs2 | xcdec] @ A1 + gate epilogue
  f32x4 acc2[8];
#pragma unroll
  for (int nf = 0; nf < 8; nf++) acc2[nf] = (f32x4){0.f, 0.f, 0.f, 0.f};
  int rl0 = rowbase + mrow;
#pragma unroll
  for (int ks = 0; ks < 8; ks++) {
    short8 a;
    if (ks < 4) {
      int colg = ks * 4 + kg;
      a = *(const short8*)&xs2L[rl0 * 128 + ((colg ^ mrow) << 3)];
    } else {
      a = ok ? *(const short8*)(Xc + (size_t)r0 * 128 + (ks - 4) * 32 + kg * 8) : zero8();
    }
    const short* bb = A1p + (size_t)(ks * 8) * 512 + lane * 8;
#pragma unroll
    for (int nf = 0; nf < 8; nf++) {
      short8 b = *(const short8*)(bb + (nf << 9));
      acc2[nf] = __builtin_amdgcn_mfma_f32_16x16x32_bf16(a, b, acc2[nf], 0, 0, 0);
    }
  }
  {
    float bias[8], w20[8], w21[8];
#pragma unroll
    for (int nf = 0; nf < 8; nf++) {
      int cc = nf * 16 + col16;
      bias[nf] = ab1[cc];
      w20[nf] = A2[2 * cc];
      w21[nf] = A2[2 * cc + 1];
    }
    float b20 = ab2[0], b21 = ab2[1];
#pragma unroll
    for (int r = 0; r < 4; r++) {
      float u0 = 0.f, u1 = 0.f;
#pragma unroll
      for (int nf = 0; nf < 8; nf++) {
        float tv = fmaxf(acc2[nf][r] + bias[nf], 0.f);
        u0 = fmaf(tv, w20[nf], u0);
        u1 = fmaf(tv, w21[nf], u1);
      }
#pragma unroll
      for (int off = 1; off < 16; off <<= 1) {
        u0 += __shfl_xor(u0, off);
        u1 += __shfl_xor(u1, off);
      }
      int rl = rowbase + g * 4 + r;
      int row = m0 + rl;
      if (row < M) {
        float ua = u0 + b20, ub = u1 + b21;
        float mx = fmaxf(ua, ub);
        float e0 = __expf(ua - mx), e1 = __expf(ub - mx);
        float inv = 1.f / (e0 + e1);
        float w0 = e0 * inv, w1 = e1 * inv;
        int p = col16;
        const unsigned short* xsp = &xs2L[rl * 128 + ((p ^ (rl & 15)) << 3)];
        const unsigned short* xcp = Xc + (size_t)row * 128 + p * 8;
        unsigned short* fp = &fusL[rl * 128 + ((p ^ (rl & 15)) << 3)];
        float* op = fused + (size_t)row * 128 + p * 8;
        float4 o0, o1;
        unsigned cx0 = *(const unsigned*)(xcp + 0), cx1 = *(const unsigned*)(xcp + 2);
        unsigned cx2 = *(const unsigned*)(xcp + 4), cx3 = *(const unsigned*)(xcp + 6);
        o0.x = w0 * bf2f(xsp[0]) + w1 * bflo(cx0);
        o0.y = w0 * bf2f(xsp[1]) + w1 * bfhi(cx0);
        o0.z = w0 * bf2f(xsp[2]) + w1 * bflo(cx1);
        o0.w = w0 * bf2f(xsp[3]) + w1 * bfhi(cx1);
        o1.x = w0 * bf2f(xsp[4]) + w1 * bflo(cx2);
        o1.y = w0 * bf2f(xsp[5]) + w1 * bfhi(cx2);
        o1.z = w0 * bf2f(xsp[6]) + w1 * bflo(cx3);
        o1.w = w0 * bf2f(xsp[7]) + w1 * bfhi(cx3);
        *(float4*)op = o0;
        *(float4*)(op + 4) = o1;
        fp[0] = f2bf(o0.x); fp[1] = f2bf(o0.y); fp[2] = f2bf(o0.z); fp[3] = f2bf(o0.w);
        fp[4] = f2bf(o1.x); fp[5] = f2bf(o1.y); fp[6] = f2bf(o1.z); fp[7] = f2bf(o1.w);
      } else {
        unsigned short* fp = &fusL[rl * 128 + ((col16 ^ (rl & 15)) << 3)];
#pragma unroll
        for (int q = 0; q < 8; q++) fp[q] = 0;
      }
    }
  }
  __syncthreads();

  // Stage 3: heads from fusL
  f32x4 acc3[5];
#pragma unroll
  for (int nf = 0; nf < 5; nf++) acc3[nf] = (f32x4){0.f, 0.f, 0.f, 0.f};
#pragma unroll
  for (int ks = 0; ks < 4; ks++) {
    int colg = ks * 4 + kg;
    short8 a = *(const short8*)&fusL[rl0 * 128 + ((colg ^ mrow) << 3)];
    const short* bb = Bh + (size_t)(ks * 5) * 512 + lane * 8;
#pragma unroll
    for (int nf = 0; nf < 5; nf++) {
      short8 b = *(const short8*)(bb + (nf << 9));
      acc3[nf] = __builtin_amdgcn_mfma_f32_16x16x32_bf16(a, b, acc3[nf], 0, 0, 0);
    }
  }
  {
    float bh[4], d20[4], d21[4];
#pragma unroll
    for (int nf = 0; nf < 4; nf++) {
      int h = col16 + 16 * nf;
      bh[nf] = db1[h];
      d20[nf] = D2[h * 2];
      d21[nf] = D2[h * 2 + 1];
    }
    float bc = (col16 < 9) ? bcls[col16] : 0.f;
    float b20 = db2[0], b21 = db2[1];
#pragma unroll
    for (int r = 0; r < 4; r++) {
      float p0 = 0.f, p1 = 0.f;
#pragma unroll
      for (int nf = 0; nf < 4; nf++) {
        float hv = fmaxf(acc3[nf][r] + bh[nf], 0.f);
        p0 = fmaf(hv, d20[nf], p0);
        p1 = fmaf(hv, d21[nf], p1);
      }
#pragma unroll
      for (int off = 1; off < 16; off <<= 1) {
        p0 += __shfl_xor(p0, off);
        p1 += __shfl_xor(p1, off);
      }
      int row = m0 + rowbase + g * 4 + r;
      if (row < M) {
        if (col16 < 9) cls_out[(size_t)row * 9 + col16] = acc3[4][r] + bc;
        if (col16 == 0) {
          dom_out[(size_t)row * 2 + 0] = p0 + b20;
          dom_out[(size_t)row * 2 + 1] = p1 + b21;
        }
      }
    }
  }
}

extern "C" void kernel_launch(void* const* d_in, const int* in_sizes, int n_in,
                              void* d_out, int out_size, void* d_ws, size_t ws_size,
                              hipStream_t stream) {
  const float* x_s = (const float*)d_in[0];
  const float* x_c = (const float*)d_in[1];
  const float* Q = (const float*)d_in[2];
  const int* eis = (const int*)d_in[3];
  const int* eic = (const int*)d_in[4];
  const float* W1s = (const float*)d_in[5];
  const float* b1s = (const float*)d_in[6];
  const float* W2s = (const float*)d_in[7];
  const float* b2s = (const float*)d_in[8];
  const float* W1c = (const float*)d_in[9];
  const float* b1c = (const float*)d_in[10];
  const float* W2c = (const float*)d_in[11];
  const float* b2c = (const float*)d_in[12];
  const float* A1 = (const float*)d_in[13];
  const float* ab1 = (const float*)d_in[14];
  const float* A2 = (const float*)d_in[15];
  const float* ab2 = (const float*)d_in[16];
  const float* Wcls = (const float*)d_in[17];
  const float* bcls = (const float*)d_in[18];
  const float* D1 = (const float*)d_in[19];
  const float* db1 = (const float*)d_in[20];
  const float* D2 = (const float*)d_in[21];
  const float* db2 = (const float*)d_in[22];

  float* out_cls = (float*)d_out;
  float* out_dom = out_cls + (size_t)kNS * 9;
  float* out_fus = out_dom + (size_t)kNS * 2;

  char* p = (char*)d_ws;
  auto alloc = [&](size_t bytes) -> void* {
    void* r = (void*)p;
    p += (bytes + 255) & ~(size_t)255;
    return r;
  };
  // sample graph
  int* deg_s = (int*)alloc((size_t)kNS * 4);
  float* dis_s = (float*)alloc((size_t)kNS * 4);
  int* nstarts_s = (int*)alloc((size_t)kNS * 4);
  int* counts_s = (int*)alloc((size_t)kNB8 * 4);
  int* bstarts_s = (int*)alloc((size_t)(kNB8 + 1) * 4);
  int* bcursor_s = (int*)alloc((size_t)kNB8 * 4);
  int* srow_s = (int*)alloc((size_t)kES * 4);
  unsigned* edg_s = (unsigned*)alloc((size_t)kES * 4);
  // cluster graph + features
  int* srow_c = (int*)alloc((size_t)kEC * 4);
  unsigned short* yc = (unsigned short*)alloc((size_t)kNC * 64 * 2);
  unsigned short* gtc = (unsigned short*)alloc((size_t)kNC * 64 * 2);
  unsigned short* xc2b = (unsigned short*)alloc((size_t)kNC * 128 * 2);
  // sample features
  unsigned* zs = (unsigned*)alloc((size_t)kNS * 16);
  unsigned short* ys = (unsigned short*)alloc((size_t)kNS * 64 * 2);
  unsigned short* gts = (unsigned short*)alloc((size_t)kNS * 64 * 2);
  unsigned short* xcdb = (unsigned short*)alloc((size_t)kNS * 128 * 2);
  // packed B operands
  short* Bq = (short*)alloc((size_t)512 * 128 * 2);
  short* A1p = (short*)alloc((size_t)256 * 128 * 2);
  short* Bh = (short*)alloc((size_t)128 * 80 * 2);
  short* W2sp = (short*)alloc((size_t)64 * 128 * 2);
  (void)ws_size; (void)in_sizes; (void)n_in; (void)out_size;

  hipMemsetAsync(counts_s, 0, (size_t)kNB8 * 4, stream);

  // fat0: cluster mega-block || passA histogram
  k_fat0<<<1 + kNBLK, 256, 0, stream>>>(eic, eic + kEC, x_c, W1c, b1c, W2c, b2c,
                                        A1, D1, Wcls, W2s,
                                        srow_c, yc, gtc, xc2b, Bq, A1p, Bh, W2sp,
                                        eis + kES, kES, counts_s);
  k_scan_flat<<<1, 256, 0, stream>>>(counts_s, kNB8, bstarts_s, bcursor_s);

  // fatB: gemm_q 1/3 || passB
  k_fatB<<<kG1 + kNBLK, 256, 0, stream>>>(Q, Bq, xcdb, kNS, eis, eis + kES, kES, bcursor_s, edg_s);
  // fatC: gemm_q 1/3 || passC (CSR + dis + z)
  k_fatC<<<kG2 + kNB, 256, 0, stream>>>(Q, Bq, xcdb, kNS, edg_s, bstarts_s, deg_s, nstarts_s, dis_s, srow_s, x_s, zs);

  // sample layer-1 (fused agg7 + lin7b)
  k_agg7lin<<<(kNS + 255) / 256, 256, 0, stream>>>(zs, nstarts_s, deg_s, srow_s, dis_s, W1s, b1s, ys, kNS);

  // fatA: gemm_q 1/3 || agg64
  k_fatA<<<kG3 + kAgg64Blocks, 256, 0, stream>>>(Q, Bq, xcdb, ys, nstarts_s, deg_s, srow_s, dis_s, gts, kNS);

  // tail: lin64x128 + fuse-gate + heads
  k_tail<<<(kNS + 63) / 64, 256, 0, stream>>>(gts, W2sp, b2s, xcdb, A1p, ab1, A2, ab2,
                                              Bh, bcls, db1, D2, db2,
                                              out_fus, out_cls, out_dom, kNS);
}

// Round 13
// 435.843 us; speedup vs baseline: 3.0071x; 3.0071x over previous
//
#include <hip/hip_runtime.h>
#include <cstdint>
#include <cstddef>

static constexpr int kNS = 100000;
static constexpr int kNC = 512;
static constexpr int kES = 3200000;
static constexpr int kEC = 16384;

static constexpr int kNB = (kNS + 63) / 64;        // 1563 coarse buckets
static constexpr int kNB8 = kNB * 8;
static constexpr int kCHUNK = 8192;
static constexpr int kNBLK = (kES + kCHUNK - 1) / kCHUNK;  // 391

static constexpr int kGemmQBlocks = (kNS + 63) / 64;   // 1563
static constexpr int kAgg64Blocks = (kNS + 7) / 8;     // 12500
static constexpr int kG1 = 625;
static constexpr int kG2 = 469;
static constexpr int kG3 = kGemmQBlocks - kG1 - kG2;

typedef __attribute__((ext_vector_type(8))) short short8;
typedef __attribute__((ext_vector_type(4))) float f32x4;

__device__ __forceinline__ unsigned short f2bf(float f) {
  union { float f; unsigned u; } v; v.f = f;
  unsigned u = v.u;
  unsigned r = (u + 0x7fffu + ((u >> 16) & 1u)) >> 16;
  return (unsigned short)r;
}
__device__ __forceinline__ float bflo(unsigned v) { return __uint_as_float(v << 16); }
__device__ __forceinline__ float bfhi(unsigned v) { return __uint_as_float(v & 0xffff0000u); }
__device__ __forceinline__ float bf2f(unsigned short s) { return __uint_as_float(((unsigned)s) << 16); }
__device__ __forceinline__ unsigned pk2(float a, float b) {
  return (unsigned)f2bf(a) | ((unsigned)f2bf(b) << 16);
}

// ---------------- passA: bucket histogram ----------------
__global__ __launch_bounds__(256) void k_passA(const int* __restrict__ col, int E,
                                               int* __restrict__ counts) {
  __shared__ int hist[kNB];
  int t = threadIdx.x, bid = blockIdx.x;
  for (int j = t; j < kNB; j += 256) hist[j] = 0;
  __syncthreads();
  int base = bid * kCHUNK;
#pragma unroll 4
  for (int i = 0; i < kCHUNK / 256; i++) {
    int e = base + i * 256 + t;
    if (e < E) atomicAdd(&hist[col[e] >> 6], 1);
  }
  __syncthreads();
  int sub = bid & 7;
  for (int j = t; j < kNB; j += 256) {
    int v = hist[j];
    if (v) atomicAdd(&counts[j * 8 + sub], v);
  }
}

// exclusive scan of n flat counters -> starts[n+1], cursor copy (+ optional dis from counts)
__global__ void k_scan_flat(const int* __restrict__ cnt, int n, int* __restrict__ starts,
                            int* __restrict__ cursor, float* __restrict__ dis) {
  __shared__ int s[256];
  int t = threadIdx.x;
  int run = 0;
  for (int base = 0; base < n; base += 256) {
    int i = base + t;
    int v = (i < n) ? cnt[i] : 0;
    s[t] = v;
    __syncthreads();
    for (int o = 1; o < 256; o <<= 1) {
      int x = (t >= o) ? s[t - o] : 0;
      __syncthreads();
      s[t] += x;
      __syncthreads();
    }
    if (i < n) {
      int ex = run + s[t] - v;
      starts[i] = ex;
      cursor[i] = ex;
      if (dis) dis[i] = rsqrtf((float)(v + 1));
    }
    int tot = s[255];
    __syncthreads();
    run += tot;
  }
  if (t == 0) starts[n] = run;
}

// ---------------- passB body ----------------
__device__ __forceinline__ void passB_body(int bid, int t, const int* __restrict__ row,
                                           const int* __restrict__ col, int E,
                                           int* __restrict__ cursor, unsigned* __restrict__ edg) {
  __shared__ int hist[kNB];
  int sub = bid & 7;
  for (int j = t; j < kNB; j += 256) hist[j] = 0;
  __syncthreads();
  int base = bid * kCHUNK;
#pragma unroll 4
  for (int i = 0; i < kCHUNK / 256; i++) {
    int e = base + i * 256 + t;
    if (e < E) atomicAdd(&hist[col[e] >> 6], 1);
  }
  __syncthreads();
  for (int j = t; j < kNB; j += 256) {
    int v = hist[j];
    hist[j] = v ? atomicAdd(&cursor[j * 8 + sub], v) : 0;
  }
  __syncthreads();
#pragma unroll 4
  for (int i = 0; i < kCHUNK / 256; i++) {
    int e = base + i * 256 + t;
    if (e < E) {
      int c = col[e];
      int pos = atomicAdd(&hist[c >> 6], 1);
      edg[pos] = ((unsigned)row[e] << 6) | (unsigned)(c & 63);
    }
  }
}

// ---------------- passC body: CSR + dis + z ----------------
__device__ __forceinline__ void passC_body(int b, int t, const unsigned* __restrict__ edg,
                                           const int* __restrict__ bstarts,
                                           int* __restrict__ deg, int* __restrict__ nstarts,
                                           float* __restrict__ dis, int* __restrict__ srow,
                                           const float* __restrict__ x, unsigned* __restrict__ z, int N) {
  __shared__ int ldeg[64];
  __shared__ int lcur[64];
  int s0 = bstarts[b * 8], s1 = bstarts[b * 8 + 8];
  if (t < 64) ldeg[t] = 0;
  __syncthreads();
  for (int i = s0 + t; i < s1; i += 256) atomicAdd(&ldeg[edg[i] & 63u], 1);
  __syncthreads();
  if (t < 64) {
    int own = ldeg[t];
    int incl = own;
#pragma unroll
    for (int off = 1; off < 64; off <<= 1) {
      int o = __shfl_up(incl, off);
      if (t >= off) incl += o;
    }
    int st = s0 + incl - own;
    lcur[t] = st;
    int g = b * 64 + t;
    if (g < N) {
      deg[g] = own;
      nstarts[g] = st;
      float d = rsqrtf((float)(own + 1));
      dis[g] = d;
      const float* xr = x + (size_t)g * 7;
      uint4 o4 = {pk2(xr[0] * d, xr[1] * d), pk2(xr[2] * d, xr[3] * d),
                  pk2(xr[4] * d, xr[5] * d), (unsigned)f2bf(xr[6] * d)};
      *(uint4*)(z + (size_t)g * 4) = o4;
    }
  }
  __syncthreads();
  for (int i = s0 + t; i < s1; i += 256) {
    unsigned ew = edg[i];
    int pos = atomicAdd(&lcur[ew & 63u], 1);
    srow[pos] = (int)(ew >> 6);
  }
}

// ---------------- cluster graph helpers ----------------
__global__ void k_hist(const int* __restrict__ col, int E, int* __restrict__ cnt) {
  int i = blockIdx.x * blockDim.x + threadIdx.x;
  if (i < E) atomicAdd(&cnt[col[i]], 1);
}

__global__ void k_scatter(const int* __restrict__ row, const int* __restrict__ col, int E,
                          int* __restrict__ cursor, int* __restrict__ srow) {
  int i = blockIdx.x * blockDim.x + threadIdx.x;
  if (i < E) {
    int pos = atomicAdd(&cursor[col[i]], 1);
    srow[pos] = row[i];
  }
}

// ---------------- z = x * dis (cluster) ----------------
__global__ __launch_bounds__(256) void k_z(const float* __restrict__ x, const float* __restrict__ dis,
                                           unsigned* __restrict__ z, int N) {
  int r = blockIdx.x * 256 + threadIdx.x;
  if (r >= N) return;
  const float* xr = x + (size_t)r * 7;
  float d = dis[r];
  uint4 o = {pk2(xr[0] * d, xr[1] * d), pk2(xr[2] * d, xr[3] * d),
             pk2(xr[4] * d, xr[5] * d), (unsigned)f2bf(xr[6] * d)};
  *(uint4*)(z + (size_t)r * 4) = o;
}

// ---------------- agg64 body ----------------
__device__ __forceinline__ void agg64_body(int bid, int t,
                                           const unsigned short* __restrict__ ys,
                                           const int* __restrict__ starts, const int* __restrict__ cnt,
                                           const int* __restrict__ srow, const float* __restrict__ dis,
                                           unsigned short* __restrict__ out, int N) {
  constexpr int F = 64, LPN = 32;
  int c = bid * (256 / LPN) + t / LPN;
  if (c >= N) return;
  int fi = (t % LPN) * 2;
  unsigned v = *(const unsigned*)(ys + (size_t)c * F + fi);
  float ax = bflo(v), ay = bfhi(v);
  int s0 = starts[c], n = cnt[c];
  const int* sp = srow + s0;
  int e = 0;
  for (; e + 8 <= n; e += 8) {
    int r0 = sp[e], r1 = sp[e + 1], r2 = sp[e + 2], r3 = sp[e + 3];
    int r4 = sp[e + 4], r5 = sp[e + 5], r6 = sp[e + 6], r7 = sp[e + 7];
    unsigned v0 = *(const unsigned*)(ys + (size_t)r0 * F + fi);
    unsigned v1 = *(const unsigned*)(ys + (size_t)r1 * F + fi);
    unsigned v2 = *(const unsigned*)(ys + (size_t)r2 * F + fi);
    unsigned v3 = *(const unsigned*)(ys + (size_t)r3 * F + fi);
    unsigned v4 = *(const unsigned*)(ys + (size_t)r4 * F + fi);
    unsigned v5 = *(const unsigned*)(ys + (size_t)r5 * F + fi);
    unsigned v6 = *(const unsigned*)(ys + (size_t)r6 * F + fi);
    unsigned v7 = *(const unsigned*)(ys + (size_t)r7 * F + fi);
    ax += bflo(v0) + bflo(v1) + bflo(v2) + bflo(v3) + bflo(v4) + bflo(v5) + bflo(v6) + bflo(v7);
    ay += bfhi(v0) + bfhi(v1) + bfhi(v2) + bfhi(v3) + bfhi(v4) + bfhi(v5) + bfhi(v6) + bfhi(v7);
  }
  for (; e + 4 <= n; e += 4) {
    int r0 = sp[e], r1 = sp[e + 1], r2 = sp[e + 2], r3 = sp[e + 3];
    unsigned v0 = *(const unsigned*)(ys + (size_t)r0 * F + fi);
    unsigned v1 = *(const unsigned*)(ys + (size_t)r1 * F + fi);
    unsigned v2 = *(const unsigned*)(ys + (size_t)r2 * F + fi);
    unsigned v3 = *(const unsigned*)(ys + (size_t)r3 * F + fi);
    ax += bflo(v0) + bflo(v1) + bflo(v2) + bflo(v3);
    ay += bfhi(v0) + bfhi(v1) + bfhi(v2) + bfhi(v3);
  }
  for (; e < n; e++) {
    unsigned vv = *(const unsigned*)(ys + (size_t)sp[e] * F + fi);
    ax += bflo(vv);
    ay += bfhi(vv);
  }
  float d = dis[c];
  *(unsigned*)(out + (size_t)c * F + fi) = pk2(ax * d, ay * d);
}

__global__ __launch_bounds__(256) void k_agg64(const unsigned short* __restrict__ ys,
                                               const int* __restrict__ starts, const int* __restrict__ cnt,
                                               const int* __restrict__ srow, const float* __restrict__ dis,
                                               unsigned short* __restrict__ out, int N) {
  agg64_body(blockIdx.x, threadIdx.x, ys, starts, cnt, srow, dis, out, N);
}

// ---------------- fused agg7+lin7b: thread per node ----------------
__global__ __launch_bounds__(256) void k_agg7lin(const unsigned* __restrict__ z,
                                                 const int* __restrict__ starts, const int* __restrict__ cnt,
                                                 const int* __restrict__ srow, const float* __restrict__ dis,
                                                 const float* __restrict__ W1, const float* __restrict__ b1,
                                                 unsigned short* __restrict__ y, int N) {
  __shared__ float WL[7 * 64];
  __shared__ float bL[64];
  int t = threadIdx.x;
  for (int j = t; j < 448; j += 256) WL[j] = W1[j];
  if (t < 64) bL[t] = b1[t];
  __syncthreads();
  int c = blockIdx.x * 256 + t;
  if (c >= N) return;
  float a[7];
  {
    uint4 v = *(const uint4*)(z + (size_t)c * 4);
    a[0] = bflo(v.x); a[1] = bfhi(v.x); a[2] = bflo(v.y); a[3] = bfhi(v.y);
    a[4] = bflo(v.z); a[5] = bfhi(v.z); a[6] = bflo(v.w);
  }
  int s0 = starts[c], n = cnt[c];
  const int* sp = srow + s0;
  int e = 0;
  for (; e + 4 <= n; e += 4) {
    uint4 w0 = *(const uint4*)(z + (size_t)sp[e] * 4);
    uint4 w1 = *(const uint4*)(z + (size_t)sp[e + 1] * 4);
    uint4 w2 = *(const uint4*)(z + (size_t)sp[e + 2] * 4);
    uint4 w3 = *(const uint4*)(z + (size_t)sp[e + 3] * 4);
    a[0] += bflo(w0.x) + bflo(w1.x) + bflo(w2.x) + bflo(w3.x);
    a[1] += bfhi(w0.x) + bfhi(w1.x) + bfhi(w2.x) + bfhi(w3.x);
    a[2] += bflo(w0.y) + bflo(w1.y) + bflo(w2.y) + bflo(w3.y);
    a[3] += bfhi(w0.y) + bfhi(w1.y) + bfhi(w2.y) + bfhi(w3.y);
    a[4] += bflo(w0.z) + bflo(w1.z) + bflo(w2.z) + bflo(w3.z);
    a[5] += bfhi(w0.z) + bfhi(w1.z) + bfhi(w2.z) + bfhi(w3.z);
    a[6] += bflo(w0.w) + bflo(w1.w) + bflo(w2.w) + bflo(w3.w);
  }
  for (; e < n; e++) {
    uint4 w = *(const uint4*)(z + (size_t)sp[e] * 4);
    a[0] += bflo(w.x); a[1] += bfhi(w.x); a[2] += bflo(w.y); a[3] += bfhi(w.y);
    a[4] += bflo(w.z); a[5] += bfhi(w.z); a[6] += bflo(w.w);
  }
  float d = dis[c];
#pragma unroll
  for (int k = 0; k < 7; k++) a[k] *= d;
  unsigned ow[32];
#pragma unroll
  for (int j2 = 0; j2 < 32; j2++) {
    int j = j2 * 2;
    float s0v = bL[j], s1v = bL[j + 1];
#pragma unroll
    for (int k = 0; k < 7; k++) {
      s0v = fmaf(a[k], WL[k * 64 + j], s0v);
      s1v = fmaf(a[k], WL[k * 64 + j + 1], s1v);
    }
    ow[j2] = pk2(fmaxf(s0v, 0.f) * d, fmaxf(s1v, 0.f) * d);
  }
  uint4* op = (uint4*)(y + (size_t)c * 64);
#pragma unroll
  for (int q = 0; q < 8; q++) {
    uint4 v = {ow[q * 4], ow[q * 4 + 1], ow[q * 4 + 2], ow[q * 4 + 3]};
    op[q] = v;
  }
}

// ---------------- lin64x128 (cluster, scalar): xc2b = relu(gt @ W + b) ----------------
__global__ __launch_bounds__(256) void k_lin64x128(const unsigned short* __restrict__ xin, const float* __restrict__ W,
                                                   const float* __restrict__ b, unsigned short* __restrict__ hs, int N) {
  __shared__ float Ws[64 * 128];
  __shared__ float xs[32][64];
  int t = threadIdx.x;
  for (int j = t; j < 64 * 128; j += 256) Ws[j] = W[j];
  int r0 = blockIdx.x * 32;
  for (int j = t; j < 32 * 64; j += 256) {
    int r = j >> 6, k = j & 63;
    int gr = r0 + r;
    xs[r][k] = (gr < N) ? bf2f(xin[(size_t)gr * 64 + k]) : 0.f;
  }
  __syncthreads();
  int c = t & 63;
  int rb = (t >> 6) * 8;
  float a0[8], a1[8];
#pragma unroll
  for (int rr = 0; rr < 8; rr++) { a0[rr] = 0.f; a1[rr] = 0.f; }
  for (int k = 0; k < 64; k++) {
    float w0 = Ws[k * 128 + c];
    float w1 = Ws[k * 128 + c + 64];
#pragma unroll
    for (int rr = 0; rr < 8; rr++) {
      float xv = xs[rb + rr][k];
      a0[rr] = fmaf(xv, w0, a0[rr]);
      a1[rr] = fmaf(xv, w1, a1[rr]);
    }
  }
  float bb0 = b[c], bb1 = b[c + 64];
#pragma unroll
  for (int rr = 0; rr < 8; rr++) {
    int gr = r0 + rb + rr;
    if (gr < N) {
      hs[(size_t)gr * 128 + c] = f2bf(fmaxf(a0[rr] + bb0, 0.f));
      hs[(size_t)gr * 128 + c + 64] = f2bf(fmaxf(a1[rr] + bb1, 0.f));
    }
  }
}

// ---------------- combined B-operand pack: Bq, A1p, Bh, W2sp ----------------
__global__ void k_pack_all(const unsigned short* __restrict__ xc2b, const float* __restrict__ A1,
                           const float* __restrict__ D1, const float* __restrict__ Wcls,
                           const float* __restrict__ W2s,
                           short* __restrict__ Bq, short* __restrict__ A1p, short* __restrict__ Bh,
                           short* __restrict__ W2sp) {
  int i = blockIdx.x * 256 + threadIdx.x;
  if (i < 512 * 128) {
    int e = i;
    int k = e >> 7, n = e & 127;
    int frag = (k >> 5) * 8 + (n >> 4);
    int l = (n & 15) | (((k >> 3) & 3) << 4);
    Bq[(size_t)frag * 512 + l * 8 + (k & 7)] = (short)xc2b[e];
  } else if (i < 512 * 128 + 256 * 128) {
    int e = i - 512 * 128;
    int k = e >> 7, n = e & 127;
    int frag = (k >> 5) * 8 + (n >> 4);
    int l = (n & 15) | (((k >> 3) & 3) << 4);
    A1p[(size_t)frag * 512 + l * 8 + (k & 7)] = (short)f2bf(A1[e]);
  } else if (i < 512 * 128 + 256 * 128 + 128 * 80) {
    int e = i - (512 * 128 + 256 * 128);
    int k = e / 80, n = e % 80;
    float v = 0.f;
    if (n < 64) v = D1[k * 64 + n];
    else if (n < 73) v = Wcls[k * 9 + (n - 64)];
    int frag = (k >> 5) * 5 + (n >> 4);
    int l = (n & 15) | (((k >> 3) & 3) << 4);
    Bh[(size_t)frag * 512 + l * 8 + (k & 7)] = (short)f2bf(v);
  } else if (i < 512 * 128 + 256 * 128 + 128 * 80 + 64 * 128) {
    int e = i - (512 * 128 + 256 * 128 + 128 * 80);
    int k = e >> 7, n = e & 127;
    int frag = (k >> 5) * 8 + (n >> 4);
    int l = (n & 15) | (((k >> 3) & 3) << 4);
    W2sp[(size_t)frag * 512 + l * 8 + (k & 7)] = (short)f2bf(W2s[e]);
  }
}

__device__ __forceinline__ short8 zero8() {
  short8 z;
#pragma unroll
  for (int j = 0; j < 8; j++) z[j] = 0;
  return z;
}

__device__ __forceinline__ short8 cvt8(float4 v0, float4 v1) {
  short8 r;
  r[0] = (short)f2bf(v0.x); r[1] = (short)f2bf(v0.y); r[2] = (short)f2bf(v0.z); r[3] = (short)f2bf(v0.w);
  r[4] = (short)f2bf(v1.x); r[5] = (short)f2bf(v1.y); r[6] = (short)f2bf(v1.z); r[7] = (short)f2bf(v1.w);
  return r;
}

// ---------------- gemm_q body (64 rows/block, 16 rows/wave, reg double-buffered) ----------------
__device__ __forceinline__ void gemm_q_body(int bid, int t, const float* __restrict__ Q,
                                            const short* __restrict__ Bp,
                                            unsigned short* __restrict__ outb, int M) {
  int lane = t & 63;
  int wid = t >> 6;
  int m0 = bid * 64 + wid * 16;
  int mrow = lane & 15;
  int kg = lane >> 4;
  f32x4 acc[8];
#pragma unroll
  for (int nf = 0; nf < 8; nf++) acc[nf] = (f32x4){0.f, 0.f, 0.f, 0.f};
  int r0 = m0 + mrow;
  bool ok = r0 < M;
  const float* ap = Q + (size_t)r0 * 512 + kg * 8;
  const short* bl = Bp + lane * 8;
  float4 z4 = {0.f, 0.f, 0.f, 0.f};
  float4 v0 = ok ? *(const float4*)ap : z4;
  float4 v1 = ok ? *(const float4*)(ap + 4) : z4;
  for (int ks = 0; ks < 16; ks++) {
    float4 n0 = z4, n1 = z4;
    if (ks < 15 && ok) {
      n0 = *(const float4*)(ap + (ks + 1) * 32);
      n1 = *(const float4*)(ap + (ks + 1) * 32 + 4);
    }
    short8 a = cvt8(v0, v1);
    const short* bb = bl + (ks << 12);
#pragma unroll
    for (int nf = 0; nf < 8; nf++) {
      short8 b = *(const short8*)(bb + (nf << 9));
      acc[nf] = __builtin_amdgcn_mfma_f32_16x16x32_bf16(a, b, acc[nf], 0, 0, 0);
    }
    v0 = n0;
    v1 = n1;
  }
  int col = lane & 15;
  int g = lane >> 4;
#pragma unroll
  for (int nf = 0; nf < 8; nf++)
#pragma unroll
    for (int r = 0; r < 4; r++) {
      int row = m0 + g * 4 + r;
      if (row < M) outb[(size_t)row * 128 + nf * 16 + col] = f2bf(acc[nf][r]);
    }
}

// ---------------- FAT kernels ----------------
__global__ __launch_bounds__(256) void k_fatB(const float* __restrict__ Q, const short* __restrict__ Bq,
                                              unsigned short* __restrict__ xcdb, int M,
                                              const int* __restrict__ row, const int* __restrict__ col, int E,
                                              int* __restrict__ cursor, unsigned* __restrict__ edg) {
  int bid = blockIdx.x, t = threadIdx.x;
  if (bid < kG1) gemm_q_body(bid, t, Q, Bq, xcdb, M);
  else passB_body(bid - kG1, t, row, col, E, cursor, edg);
}

__global__ __launch_bounds__(256) void k_fatC(const float* __restrict__ Q, const short* __restrict__ Bq,
                                              unsigned short* __restrict__ xcdb, int M,
                                              const unsigned* __restrict__ edg, const int* __restrict__ bstarts,
                                              int* __restrict__ deg, int* __restrict__ nstarts,
                                              float* __restrict__ dis, int* __restrict__ srow,
                                              const float* __restrict__ xs, unsigned* __restrict__ zs) {
  int bid = blockIdx.x, t = threadIdx.x;
  if (bid < kG2) gemm_q_body(kG1 + bid, t, Q, Bq, xcdb, M);
  else passC_body(bid - kG2, t, edg, bstarts, deg, nstarts, dis, srow, xs, zs, M);
}

__global__ __launch_bounds__(256) void k_fatA(const float* __restrict__ Q, const short* __restrict__ Bq,
                                              unsigned short* __restrict__ xcdb,
                                              const unsigned short* __restrict__ ys,
                                              const int* __restrict__ starts, const int* __restrict__ cnt,
                                              const int* __restrict__ srow, const float* __restrict__ dis,
                                              unsigned short* __restrict__ gt, int M) {
  int bid = blockIdx.x, t = threadIdx.x;
  if (bid < kG3) gemm_q_body(kG1 + kG2 + bid, t, Q, Bq, xcdb, M);
  else agg64_body(bid - kG3, t, ys, starts, cnt, srow, dis, gt, M);
}

// ---------------- TAIL: lin64x128 (MFMA) + fuse-gate + heads, LDS-staged ----------------
__global__ __launch_bounds__(256) void k_tail(const unsigned short* __restrict__ gts,
                                              const short* __restrict__ W2p, const float* __restrict__ b2,
                                              const unsigned short* __restrict__ Xc,
                                              const short* __restrict__ A1p, const float* __restrict__ ab1,
                                              const float* __restrict__ A2, const float* __restrict__ ab2,
                                              const short* __restrict__ Bh, const float* __restrict__ bcls,
                                              const float* __restrict__ db1, const float* __restrict__ D2,
                                              const float* __restrict__ db2,
                                              float* __restrict__ fused, float* __restrict__ cls_out,
                                              float* __restrict__ dom_out, int M) {
  __shared__ unsigned short xs2L[64 * 128];
  __shared__ unsigned short fusL[64 * 128];
  int t = threadIdx.x;
  int lane = t & 63;
  int wid = t >> 6;
  int m0 = blockIdx.x * 64;
  int mrow = lane & 15;
  int kg = lane >> 4;
  int rowbase = wid * 16;
  int r0 = m0 + rowbase + mrow;
  bool ok = r0 < M;
  int col16 = mrow, g = kg;

  // Stage 1: xs2 = relu(gts @ W2 + b2)
  f32x4 acc1[8];
#pragma unroll
  for (int nf = 0; nf < 8; nf++) acc1[nf] = (f32x4){0.f, 0.f, 0.f, 0.f};
#pragma unroll
  for (int ks = 0; ks < 2; ks++) {
    short8 a = ok ? *(const short8*)(gts + (size_t)r0 * 64 + ks * 32 + kg * 8) : zero8();
    const short* bb = W2p + (size_t)(ks * 8) * 512 + lane * 8;
#pragma unroll
    for (int nf = 0; nf < 8; nf++) {
      short8 b = *(const short8*)(bb + (nf << 9));
      acc1[nf] = __builtin_amdgcn_mfma_f32_16x16x32_bf16(a, b, acc1[nf], 0, 0, 0);
    }
  }
#pragma unroll
  for (int nf = 0; nf < 8; nf++)
#pragma unroll
    for (int r = 0; r < 4; r++) {
      int col = nf * 16 + col16;
      int rl = rowbase + g * 4 + r;
      float v = fmaxf(acc1[nf][r] + b2[col], 0.f);
      xs2L[rl * 128 + (((col >> 3) ^ (rl & 15)) << 3) + (col & 7)] = f2bf(v);
    }
  __syncthreads();

  // Stage 2: fuse GEMM [xs2 | xcdec] @ A1 + gate epilogue
  f32x4 acc2[8];
#pragma unroll
  for (int nf = 0; nf < 8; nf++) acc2[nf] = (f32x4){0.f, 0.f, 0.f, 0.f};
  int rl0 = rowbase + mrow;
#pragma unroll
  for (int ks = 0; ks < 8; ks++) {
    short8 a;
    if (ks < 4) {
      int colg = ks * 4 + kg;
      a = *(const short8*)&xs2L[rl0 * 128 + ((colg ^ mrow) << 3)];
    } else {
      a = ok ? *(const short8*)(Xc + (size_t)r0 * 128 + (ks - 4) * 32 + kg * 8) : zero8();
    }
    const short* bb = A1p + (size_t)(ks * 8) * 512 + lane * 8;
#pragma unroll
    for (int nf = 0; nf < 8; nf++) {
      short8 b = *(const short8*)(bb + (nf << 9));
      acc2[nf] = __builtin_amdgcn_mfma_f32_16x16x32_bf16(a, b, acc2[nf], 0, 0, 0);
    }
  }
  {
    float bias[8], w20[8], w21[8];
#pragma unroll
    for (int nf = 0; nf < 8; nf++) {
      int cc = nf * 16 + col16;
      bias[nf] = ab1[cc];
      w20[nf] = A2[2 * cc];
      w21[nf] = A2[2 * cc + 1];
    }
    float b20 = ab2[0], b21 = ab2[1];
#pragma unroll
    for (int r = 0; r < 4; r++) {
      float u0 = 0.f, u1 = 0.f;
#pragma unroll
      for (int nf = 0; nf < 8; nf++) {
        float tv = fmaxf(acc2[nf][r] + bias[nf], 0.f);
        u0 = fmaf(tv, w20[nf], u0);
        u1 = fmaf(tv, w21[nf], u1);
      }
#pragma unroll
      for (int off = 1; off < 16; off <<= 1) {
        u0 += __shfl_xor(u0, off);
        u1 += __shfl_xor(u1, off);
      }
      int rl = rowbase + g * 4 + r;
      int row = m0 + rl;
      if (row < M) {
        float ua = u0 + b20, ub = u1 + b21;
        float mx = fmaxf(ua, ub);
        float e0 = __expf(ua - mx), e1 = __expf(ub - mx);
        float inv = 1.f / (e0 + e1);
        float w0 = e0 * inv, w1 = e1 * inv;
        int p = col16;
        const unsigned short* xsp = &xs2L[rl * 128 + ((p ^ (rl & 15)) << 3)];
        const unsigned short* xcp = Xc + (size_t)row * 128 + p * 8;
        unsigned short* fp = &fusL[rl * 128 + ((p ^ (rl & 15)) << 3)];
        float* op = fused + (size_t)row * 128 + p * 8;
        float4 o0, o1;
        unsigned cx0 = *(const unsigned*)(xcp + 0), cx1 = *(const unsigned*)(xcp + 2);
        unsigned cx2 = *(const unsigned*)(xcp + 4), cx3 = *(const unsigned*)(xcp + 6);
        o0.x = w0 * bf2f(xsp[0]) + w1 * bflo(cx0);
        o0.y = w0 * bf2f(xsp[1]) + w1 * bfhi(cx0);
        o0.z = w0 * bf2f(xsp[2]) + w1 * bflo(cx1);
        o0.w = w0 * bf2f(xsp[3]) + w1 * bfhi(cx1);
        o1.x = w0 * bf2f(xsp[4]) + w1 * bflo(cx2);
        o1.y = w0 * bf2f(xsp[5]) + w1 * bfhi(cx2);
        o1.z = w0 * bf2f(xsp[6]) + w1 * bflo(cx3);
        o1.w = w0 * bf2f(xsp[7]) + w1 * bfhi(cx3);
        *(float4*)op = o0;
        *(float4*)(op + 4) = o1;
        fp[0] = f2bf(o0.x); fp[1] = f2bf(o0.y); fp[2] = f2bf(o0.z); fp[3] = f2bf(o0.w);
        fp[4] = f2bf(o1.x); fp[5] = f2bf(o1.y); fp[6] = f2bf(o1.z); fp[7] = f2bf(o1.w);
      } else {
        unsigned short* fp = &fusL[rl * 128 + ((col16 ^ (rl & 15)) << 3)];
#pragma unroll
        for (int q = 0; q < 8; q++) fp[q] = 0;
      }
    }
  }
  __syncthreads();

  // Stage 3: heads from fusL
  f32x4 acc3[5];
#pragma unroll
  for (int nf = 0; nf < 5; nf++) acc3[nf] = (f32x4){0.f, 0.f, 0.f, 0.f};
#pragma unroll
  for (int ks = 0; ks < 4; ks++) {
    int colg = ks * 4 + kg;
    short8 a = *(const short8*)&fusL[rl0 * 128 + ((colg ^ mrow) << 3)];
    const short* bb = Bh + (size_t)(ks * 5) * 512 + lane * 8;
#pragma unroll
    for (int nf = 0; nf < 5; nf++) {
      short8 b = *(const short8*)(bb + (nf << 9));
      acc3[nf] = __builtin_amdgcn_mfma_f32_16x16x32_bf16(a, b, acc3[nf], 0, 0, 0);
    }
  }
  {
    float bh[4], d20[4], d21[4];
#pragma unroll
    for (int nf = 0; nf < 4; nf++) {
      int h = col16 + 16 * nf;
      bh[nf] = db1[h];
      d20[nf] = D2[h * 2];
      d21[nf] = D2[h * 2 + 1];
    }
    float bc = (col16 < 9) ? bcls[col16] : 0.f;
    float b20 = db2[0], b21 = db2[1];
#pragma unroll
    for (int r = 0; r < 4; r++) {
      float p0 = 0.f, p1 = 0.f;
#pragma unroll
      for (int nf = 0; nf < 4; nf++) {
        float hv = fmaxf(acc3[nf][r] + bh[nf], 0.f);
        p0 = fmaf(hv, d20[nf], p0);
        p1 = fmaf(hv, d21[nf], p1);
      }
#pragma unroll
      for (int off = 1; off < 16; off <<= 1) {
        p0 += __shfl_xor(p0, off);
        p1 += __shfl_xor(p1, off);
      }
      int row = m0 + rowbase + g * 4 + r;
      if (row < M) {
        if (col16 < 9) cls_out[(size_t)row * 9 + col16] = acc3[4][r] + bc;
        if (col16 == 0) {
          dom_out[(size_t)row * 2 + 0] = p0 + b20;
          dom_out[(size_t)row * 2 + 1] = p1 + b21;
        }
      }
    }
  }
}

extern "C" void kernel_launch(void* const* d_in, const int* in_sizes, int n_in,
                              void* d_out, int out_size, void* d_ws, size_t ws_size,
                              hipStream_t stream) {
  const float* x_s = (const float*)d_in[0];
  const float* x_c = (const float*)d_in[1];
  const float* Q = (const float*)d_in[2];
  const int* eis = (const int*)d_in[3];
  const int* eic = (const int*)d_in[4];
  const float* W1s = (const float*)d_in[5];
  const float* b1s = (const float*)d_in[6];
  const float* W2s = (const float*)d_in[7];
  const float* b2s = (const float*)d_in[8];
  const float* W1c = (const float*)d_in[9];
  const float* b1c = (const float*)d_in[10];
  const float* W2c = (const float*)d_in[11];
  const float* b2c = (const float*)d_in[12];
  const float* A1 = (const float*)d_in[13];
  const float* ab1 = (const float*)d_in[14];
  const float* A2 = (const float*)d_in[15];
  const float* ab2 = (const float*)d_in[16];
  const float* Wcls = (const float*)d_in[17];
  const float* bcls = (const float*)d_in[18];
  const float* D1 = (const float*)d_in[19];
  const float* db1 = (const float*)d_in[20];
  const float* D2 = (const float*)d_in[21];
  const float* db2 = (const float*)d_in[22];

  float* out_cls = (float*)d_out;
  float* out_dom = out_cls + (size_t)kNS * 9;
  float* out_fus = out_dom + (size_t)kNS * 2;

  char* p = (char*)d_ws;
  auto alloc = [&](size_t bytes) -> void* {
    void* r = (void*)p;
    p += (bytes + 255) & ~(size_t)255;
    return r;
  };
  // sample graph
  int* deg_s = (int*)alloc((size_t)kNS * 4);
  float* dis_s = (float*)alloc((size_t)kNS * 4);
  int* nstarts_s = (int*)alloc((size_t)kNS * 4);
  int* counts_s = (int*)alloc((size_t)kNB8 * 4);
  int* bstarts_s = (int*)alloc((size_t)(kNB8 + 1) * 4);
  int* bcursor_s = (int*)alloc((size_t)kNB8 * 4);
  int* srow_s = (int*)alloc((size_t)kES * 4);
  unsigned* edg_s = (unsigned*)alloc((size_t)kES * 4);
  // cluster graph + features
  int* deg_c = (int*)alloc((size_t)kNC * 4);
  int* cstarts_c = (int*)alloc((size_t)(kNC + 1) * 4);
  int* cursor_c = (int*)alloc((size_t)kNC * 4);
  float* dis_c = (float*)alloc((size_t)kNC * 4);
  int* srow_c = (int*)alloc((size_t)kEC * 4);
  unsigned* zc = (unsigned*)alloc((size_t)kNC * 16);
  unsigned short* yc = (unsigned short*)alloc((size_t)kNC * 64 * 2);
  unsigned short* gtc = (unsigned short*)alloc((size_t)kNC * 64 * 2);
  unsigned short* xc2b = (unsigned short*)alloc((size_t)kNC * 128 * 2);
  // sample features
  unsigned* zs = (unsigned*)alloc((size_t)kNS * 16);
  unsigned short* ys = (unsigned short*)alloc((size_t)kNS * 64 * 2);
  unsigned short* gts = (unsigned short*)alloc((size_t)kNS * 64 * 2);
  unsigned short* xcdb = (unsigned short*)alloc((size_t)kNS * 128 * 2);
  // packed B operands
  short* Bq = (short*)alloc((size_t)512 * 128 * 2);
  short* A1p = (short*)alloc((size_t)256 * 128 * 2);
  short* Bh = (short*)alloc((size_t)128 * 80 * 2);
  short* W2sp = (short*)alloc((size_t)64 * 128 * 2);
  (void)ws_size; (void)in_sizes; (void)n_in; (void)out_size;

  hipMemsetAsync(counts_s, 0, (size_t)kNB8 * 4, stream);
  hipMemsetAsync(deg_c, 0, (size_t)kNC * 4, stream);

  // sample: bucket histogram + flat scan
  k_passA<<<kNBLK, 256, 0, stream>>>(eis + kES, kES, counts_s);
  k_scan_flat<<<1, 256, 0, stream>>>(counts_s, kNB8, bstarts_s, bcursor_s, nullptr);

  // cluster chain (parallel small kernels)
  k_hist<<<(kEC + 255) / 256, 256, 0, stream>>>(eic + kEC, kEC, deg_c);
  k_scan_flat<<<1, 256, 0, stream>>>(deg_c, kNC, cstarts_c, cursor_c, dis_c);
  k_scatter<<<(kEC + 255) / 256, 256, 0, stream>>>(eic, eic + kEC, kEC, cursor_c, srow_c);
  k_z<<<(kNC + 255) / 256, 256, 0, stream>>>(x_c, dis_c, zc, kNC);
  k_agg7lin<<<(kNC + 255) / 256, 256, 0, stream>>>(zc, cstarts_c, deg_c, srow_c, dis_c, W1c, b1c, yc, kNC);
  k_agg64<<<(kNC + 7) / 8, 256, 0, stream>>>(yc, cstarts_c, deg_c, srow_c, dis_c, gtc, kNC);
  k_lin64x128<<<(kNC + 31) / 32, 256, 0, stream>>>(gtc, W2c, b2c, xc2b, kNC);
  k_pack_all<<<(512 * 128 + 256 * 128 + 128 * 80 + 64 * 128 + 255) / 256, 256, 0, stream>>>(
      xc2b, A1, D1, Wcls, W2s, Bq, A1p, Bh, W2sp);

  // fatB: gemm_q 1/3 || passB
  k_fatB<<<kG1 + kNBLK, 256, 0, stream>>>(Q, Bq, xcdb, kNS, eis, eis + kES, kES, bcursor_s, edg_s);
  // fatC: gemm_q 1/3 || passC (CSR + dis + z)
  k_fatC<<<kG2 + kNB, 256, 0, stream>>>(Q, Bq, xcdb, kNS, edg_s, bstarts_s, deg_s, nstarts_s, dis_s, srow_s, x_s, zs);

  // sample layer-1 (fused agg7 + lin7b)
  k_agg7lin<<<(kNS + 255) / 256, 256, 0, stream>>>(zs, nstarts_s, deg_s, srow_s, dis_s, W1s, b1s, ys, kNS);

  // fatA: gemm_q 1/3 || agg64
  k_fatA<<<kG3 + kAgg64Blocks, 256, 0, stream>>>(Q, Bq, xcdb, ys, nstarts_s, deg_s, srow_s, dis_s, gts, kNS);

  // tail: lin64x128 + fuse-gate + heads
  k_tail<<<(kNS + 63) / 64, 256, 0, stream>>>(gts, W2sp, b2s, xcdb, A1p, ab1, A2, ab2,
                                              Bh, bcls, db1, D2, db2,
                                              out_fus, out_cls, out_dom, kNS);
}